// Round 6
// baseline (396.334 us; speedup 1.0000x reference)
//
#include <hip/hip_runtime.h>
#include <math.h>

#define N 6000
#define FIN 300
#define HID 128
#define NH 8
#define ALPHA 0.2f
#define NBR_CAP 512
#define KSPLIT 8

typedef unsigned short u16;
typedef unsigned int u32;

static __device__ __forceinline__ u16 f2bf(float f) {
    u32 u = __float_as_uint(f);
    u32 r = (u + 0x7fff + ((u >> 16) & 1)) >> 16;   // round-to-nearest-even
    return (u16)r;
}

// K0: build neighbor lists; per-wave private segment, 1 barrier, float4 loads
__global__ void build_nbr(const float* __restrict__ adj,
                          u16* __restrict__ nbr,
                          int* __restrict__ ncnt) {
    int n = blockIdx.x;
    int t = threadIdx.x;
    int lane = t & 63, w = t >> 6;
    __shared__ u16 lbuf[4][256];
    __shared__ int wc[4];
    const int seg = N / 4;                 // 1500
    int start = w * seg, end = start + seg;
    const float* row = adj + (size_t)n * N;
    int cnt = 0;
    for (int base = start; base < end; base += 256) {
        int m0 = base + 4 * lane;
        float4 v = make_float4(0.f, 0.f, 0.f, 0.f);
        if (m0 < end) v = *(const float4*)(row + m0);
#pragma unroll
        for (int c = 0; c < 4; c++) {
            float vc = (c == 0) ? v.x : (c == 1) ? v.y : (c == 2) ? v.z : v.w;
            bool p = vc > 0.5f;
            unsigned long long mask = __ballot(p);
            if (p) {
                int pos = cnt + __popcll(mask & ((1ull << lane) - 1ull));
                if (pos < 256) lbuf[w][pos] = (u16)(m0 + c);
            }
            cnt += __popcll(mask);
        }
    }
    if (cnt > 256) cnt = 256;
    if (lane == 0) wc[w] = cnt;
    __syncthreads();
    int offset = 0;
    for (int i = 0; i < w; i++) offset += wc[i];
    for (int i = lane; i < cnt; i += 64) {
        int idx = offset + i;
        if (idx < NBR_CAP) nbr[(size_t)n * NBR_CAP + idx] = lbuf[w][i];
    }
    if (t == 0) {
        int total = wc[0] + wc[1] + wc[2] + wc[3];
        ncnt[n] = total < NBR_CAP ? total : NBR_CAP;
    }
}

// K1: Wh = x @ W_heads (fp32), plus bf16 shadow Whb; K-step 20 (300 = 15*20)
__global__ void gemm_wh(const float* __restrict__ x,
                        const float* __restrict__ W,
                        float* __restrict__ Wh,
                        u16* __restrict__ Whb) {
    int h = blockIdx.y;
    int n0 = blockIdx.x * 64;
    __shared__ float xs[64][21];
    __shared__ float bs[20][128];
    int t = threadIdx.x;
    int tx = t & 31, ty = t >> 5;
    float acc[8][4] = {};
    for (int k0 = 0; k0 < FIN; k0 += 20) {
        for (int i = t; i < 64 * 20; i += 256) {
            int r = i / 20, c = i - r * 20;
            int n = n0 + r;
            xs[r][c] = (n < N) ? x[(size_t)n * FIN + k0 + c] : 0.f;
        }
        for (int i = t; i < 20 * 128; i += 256) {
            int r = i >> 7, c = i & 127;
            bs[r][c] = W[((size_t)h * FIN + (k0 + r)) * HID + c];
        }
        __syncthreads();
#pragma unroll
        for (int kk = 0; kk < 20; kk++) {
            float b[4];
#pragma unroll
            for (int j = 0; j < 4; j++) b[j] = bs[kk][tx * 4 + j];
#pragma unroll
            for (int i = 0; i < 8; i++) {
                float a = xs[ty * 8 + i][kk];
#pragma unroll
                for (int j = 0; j < 4; j++) acc[i][j] += a * b[j];
            }
        }
        __syncthreads();
    }
    for (int i = 0; i < 8; i++) {
        int n = n0 + ty * 8 + i;
        if (n < N) {
            size_t ro = ((size_t)h * N + n) * HID + tx * 4;
            float* o = Wh + ro;
#pragma unroll
            for (int j = 0; j < 4; j++) o[j] = acc[i][j];
            ushort4 b4;
            b4.x = f2bf(acc[i][0]); b4.y = f2bf(acc[i][1]);
            b4.z = f2bf(acc[i][2]); b4.w = f2bf(acc[i][3]);
            *(ushort4*)(Whb + ro) = b4;
        }
    }
}

// K2: f1/f2 per (h,n); one wave per pair (fp32 Wh)
__global__ void calc_f(const float* __restrict__ Wh,
                       const float* __restrict__ a_heads,
                       float* __restrict__ f1, float* __restrict__ f2) {
    int t = threadIdx.x, lane = t & 63, w = t >> 6;
    int pid = blockIdx.x * 4 + w;
    int h = pid / N, n = pid - h * N;
    const float* r = Wh + ((size_t)h * N + n) * HID;
    const float* a = a_heads + (size_t)h * 2 * HID;
    float v0 = r[lane], v1 = r[64 + lane];
    float s1 = v0 * a[lane] + v1 * a[64 + lane];
    float s2 = v0 * a[128 + lane] + v1 * a[192 + lane];
    for (int d = 32; d; d >>= 1) { s1 += __shfl_xor(s1, d); s2 += __shfl_xor(s2, d); }
    if (lane == 0) { f1[h * N + n] = s1; f2[h * N + n] = s2; }
}

// K3: layer-1 fused masked-softmax + PV, per-head blocks (head-major).
// 32 streams x 8 lanes x 16 cols/thread: amortizes per-neighbor overhead.
// SGPR base + 32-bit voffset; second dwordx4 via imm offset:16.
__global__ void gat1(const u16* __restrict__ Whb,
                     const float* __restrict__ f1, const float* __restrict__ f2,
                     const u16* __restrict__ nbr,
                     const int* __restrict__ ncnt,
                     float* __restrict__ hcat) {
    int bid = blockIdx.x;
    int h = bid / N, n = bid - h * N;
    int t = threadIdx.x;
    int s = t >> 3, op = t & 7;            // 32 streams, 8 col-groups of 16
    int cnt = ncnt[n];
    const u16* lst = nbr + (size_t)n * NBR_CAP;
    __shared__ float2 wm[NBR_CAP];         // {weight, byte-offset bits}
    __shared__ float accl[32][8][17];      // padded
    __shared__ float swl[32];

    float f1c = f1[h * N + n];
    for (int i = t; i < cnt; i += 256) {
        int m = lst[i];
        float z = f1c + f2[h * N + m];
        z = (z >= 0.f) ? z : ALPHA * z;
        wm[i] = make_float2(__expf(z), __uint_as_float((u32)m << 8));
    }
    __syncthreads();

    const char* hbase = (const char*)(Whb + (size_t)h * N * HID);  // uniform -> SGPR
    const u32 opoff = (u32)op << 5;        // 16 cols * 2B = 32B per group
    float acc[16] = {};
    float sw = 0.f;
    int j = s;
    for (; j + 32 < cnt; j += 64) {
        float2 p0 = wm[j];
        float2 p1 = wm[j + 32];
        u32 o0 = __float_as_uint(p0.y) + opoff;
        u32 o1 = __float_as_uint(p1.y) + opoff;
        const uint4 va = *(const uint4*)(hbase + o0);
        const uint4 vb = *(const uint4*)(hbase + o0 + 16);
        const uint4 vc = *(const uint4*)(hbase + o1);
        const uint4 vd = *(const uint4*)(hbase + o1 + 16);
        float w0 = p0.x, w1 = p1.x;
        acc[0]  += w0 * __uint_as_float(va.x << 16);
        acc[1]  += w0 * __uint_as_float(va.x);
        acc[2]  += w0 * __uint_as_float(va.y << 16);
        acc[3]  += w0 * __uint_as_float(va.y);
        acc[4]  += w0 * __uint_as_float(va.z << 16);
        acc[5]  += w0 * __uint_as_float(va.z);
        acc[6]  += w0 * __uint_as_float(va.w << 16);
        acc[7]  += w0 * __uint_as_float(va.w);
        acc[8]  += w0 * __uint_as_float(vb.x << 16);
        acc[9]  += w0 * __uint_as_float(vb.x);
        acc[10] += w0 * __uint_as_float(vb.y << 16);
        acc[11] += w0 * __uint_as_float(vb.y);
        acc[12] += w0 * __uint_as_float(vb.z << 16);
        acc[13] += w0 * __uint_as_float(vb.z);
        acc[14] += w0 * __uint_as_float(vb.w << 16);
        acc[15] += w0 * __uint_as_float(vb.w);
        acc[0]  += w1 * __uint_as_float(vc.x << 16);
        acc[1]  += w1 * __uint_as_float(vc.x);
        acc[2]  += w1 * __uint_as_float(vc.y << 16);
        acc[3]  += w1 * __uint_as_float(vc.y);
        acc[4]  += w1 * __uint_as_float(vc.z << 16);
        acc[5]  += w1 * __uint_as_float(vc.z);
        acc[6]  += w1 * __uint_as_float(vc.w << 16);
        acc[7]  += w1 * __uint_as_float(vc.w);
        acc[8]  += w1 * __uint_as_float(vd.x << 16);
        acc[9]  += w1 * __uint_as_float(vd.x);
        acc[10] += w1 * __uint_as_float(vd.y << 16);
        acc[11] += w1 * __uint_as_float(vd.y);
        acc[12] += w1 * __uint_as_float(vd.z << 16);
        acc[13] += w1 * __uint_as_float(vd.z);
        acc[14] += w1 * __uint_as_float(vd.w << 16);
        acc[15] += w1 * __uint_as_float(vd.w);
        sw += w0 + w1;
    }
    if (j < cnt) {
        float2 p0 = wm[j];
        u32 o0 = __float_as_uint(p0.y) + opoff;
        const uint4 va = *(const uint4*)(hbase + o0);
        const uint4 vb = *(const uint4*)(hbase + o0 + 16);
        float w0 = p0.x;
        acc[0]  += w0 * __uint_as_float(va.x << 16);
        acc[1]  += w0 * __uint_as_float(va.x);
        acc[2]  += w0 * __uint_as_float(va.y << 16);
        acc[3]  += w0 * __uint_as_float(va.y);
        acc[4]  += w0 * __uint_as_float(va.z << 16);
        acc[5]  += w0 * __uint_as_float(va.z);
        acc[6]  += w0 * __uint_as_float(va.w << 16);
        acc[7]  += w0 * __uint_as_float(va.w);
        acc[8]  += w0 * __uint_as_float(vb.x << 16);
        acc[9]  += w0 * __uint_as_float(vb.x);
        acc[10] += w0 * __uint_as_float(vb.y << 16);
        acc[11] += w0 * __uint_as_float(vb.y);
        acc[12] += w0 * __uint_as_float(vb.z << 16);
        acc[13] += w0 * __uint_as_float(vb.z);
        acc[14] += w0 * __uint_as_float(vb.w << 16);
        acc[15] += w0 * __uint_as_float(vb.w);
        sw += w0;
    }
#pragma unroll
    for (int c = 0; c < 16; c++) accl[s][op][c] = acc[c];
    if (op == 0) swl[s] = sw;
    __syncthreads();

    if (t < 128) {
        int c = t;
        int og = c >> 4, cc = c & 15;
        float r = 0.f;
#pragma unroll
        for (int k = 0; k < 32; k++) r += accl[k][og][cc];
        float swt = 0.f;
#pragma unroll
        for (int k = 0; k < 32; k++) swt += swl[k];
        r /= swt;
        r = (r > 0.f) ? r : expm1f(r);
        hcat[(size_t)n * (NH * HID) + h * HID + c] = r;
    }
}

// K4: Wh2 = hcat(6000x1024) @ W_out(1024x128), split-K over 8 slices of 128.
__global__ void gemm_out(const float* __restrict__ hcat,
                         const float* __restrict__ W_out,
                         float* __restrict__ partial) {
    int n0 = blockIdx.x * 64;
    int ks = blockIdx.y;
    __shared__ float xs[64][17];
    __shared__ float bs[16][128];
    int t = threadIdx.x;
    int tx = t & 31, ty = t >> 5;
    float acc[8][4] = {};
    int kbeg = ks * 128, kend = kbeg + 128;
    for (int k0 = kbeg; k0 < kend; k0 += 16) {
        for (int i = t; i < 64 * 16; i += 256) {
            int r = i >> 4, c = i & 15;
            int n = n0 + r;
            xs[r][c] = (n < N) ? hcat[(size_t)n * 1024 + k0 + c] : 0.f;
        }
        for (int i = t; i < 16 * 128; i += 256) {
            int r = i >> 7, c = i & 127;
            bs[r][c] = W_out[(size_t)(k0 + r) * HID + c];
        }
        __syncthreads();
#pragma unroll
        for (int kk = 0; kk < 16; kk++) {
            float b[4];
#pragma unroll
            for (int j = 0; j < 4; j++) b[j] = bs[kk][tx * 4 + j];
#pragma unroll
            for (int i = 0; i < 8; i++) {
                float a = xs[ty * 8 + i][kk];
#pragma unroll
                for (int j = 0; j < 4; j++) acc[i][j] += a * b[j];
            }
        }
        __syncthreads();
    }
    float* pout = partial + (size_t)ks * N * HID;
    for (int i = 0; i < 8; i++) {
        int n = n0 + ty * 8 + i;
        if (n < N) {
#pragma unroll
            for (int j = 0; j < 4; j++)
                pout[(size_t)n * HID + tx * 4 + j] = acc[i][j];
        }
    }
}

// K4b: Wh2 = sum over the 8 K-split partials (float4 vectorized)
__global__ void reduce_wh2(const float* __restrict__ partial,
                           float* __restrict__ Wh2) {
    int idx = blockIdx.x * 256 + threadIdx.x;      // float4 index
    const int tot4 = N * HID / 4;                  // 192000
    if (idx >= tot4) return;
    float4 v = *(const float4*)(partial + 4 * (size_t)idx);
#pragma unroll
    for (int s = 1; s < KSPLIT; s++) {
        const float4 q = *(const float4*)(partial + (size_t)s * N * HID + 4 * (size_t)idx);
        v.x += q.x; v.y += q.y; v.z += q.z; v.w += q.w;
    }
    *(float4*)(Wh2 + 4 * (size_t)idx) = v;
}

// K5: g1/g2
__global__ void calc_g(const float* __restrict__ Wh2,
                       const float* __restrict__ a_out,
                       float* __restrict__ g1, float* __restrict__ g2) {
    int t = threadIdx.x, lane = t & 63, w = t >> 6;
    int n = blockIdx.x * 4 + w;
    const float* r = Wh2 + (size_t)n * HID;
    float v0 = r[lane], v1 = r[64 + lane];
    float s1 = v0 * a_out[lane] + v1 * a_out[64 + lane];
    float s2 = v0 * a_out[128 + lane] + v1 * a_out[192 + lane];
    for (int d = 32; d; d >>= 1) { s1 += __shfl_xor(s1, d); s2 += __shfl_xor(s2, d); }
    if (lane == 0) { g1[n] = s1; g2[n] = s2; }
}

// K6: layer-2 fused masked-softmax + PV (fp32, feeds output directly)
__global__ void gat2(const float* __restrict__ Wh2,
                     const float* __restrict__ g1, const float* __restrict__ g2,
                     const u16* __restrict__ nbr,
                     const int* __restrict__ ncnt,
                     float* __restrict__ out) {
    int n = blockIdx.x, t = threadIdx.x;
    int s = t >> 4, op = t & 15;
    int cnt = ncnt[n];
    const u16* lst = nbr + (size_t)n * NBR_CAP;
    __shared__ float2 wm[NBR_CAP];
    __shared__ float accl[16][16][9];
    __shared__ float swl[16];

    float g1c = g1[n];
    for (int i = t; i < cnt; i += 256) {
        int m = lst[i];
        float z = g1c + g2[m];
        z = (z >= 0.f) ? z : ALPHA * z;
        wm[i] = make_float2(__expf(z), __uint_as_float((u32)m << 9));
    }
    __syncthreads();

    const char* base = (const char*)Wh2 + (op << 5);
    float acc[8] = {};
    float sw = 0.f;
    int j = s;
    for (; j + 16 < cnt; j += 32) {
        float2 p0 = wm[j];
        float2 p1 = wm[j + 16];
        const float4 va0 = *(const float4*)(base + __float_as_uint(p0.y));
        const float4 va1 = *(const float4*)(base + __float_as_uint(p0.y) + 16);
        const float4 vb0 = *(const float4*)(base + __float_as_uint(p1.y));
        const float4 vb1 = *(const float4*)(base + __float_as_uint(p1.y) + 16);
        float w0 = p0.x, w1 = p1.x;
        acc[0] += w0 * va0.x; acc[1] += w0 * va0.y;
        acc[2] += w0 * va0.z; acc[3] += w0 * va0.w;
        acc[4] += w0 * va1.x; acc[5] += w0 * va1.y;
        acc[6] += w0 * va1.z; acc[7] += w0 * va1.w;
        acc[0] += w1 * vb0.x; acc[1] += w1 * vb0.y;
        acc[2] += w1 * vb0.z; acc[3] += w1 * vb0.w;
        acc[4] += w1 * vb1.x; acc[5] += w1 * vb1.y;
        acc[6] += w1 * vb1.z; acc[7] += w1 * vb1.w;
        sw += w0 + w1;
    }
    if (j < cnt) {
        float2 p0 = wm[j];
        const float4 va0 = *(const float4*)(base + __float_as_uint(p0.y));
        const float4 va1 = *(const float4*)(base + __float_as_uint(p0.y) + 16);
        float w0 = p0.x;
        acc[0] += w0 * va0.x; acc[1] += w0 * va0.y;
        acc[2] += w0 * va0.z; acc[3] += w0 * va0.w;
        acc[4] += w0 * va1.x; acc[5] += w0 * va1.y;
        acc[6] += w0 * va1.z; acc[7] += w0 * va1.w;
        sw += w0;
    }
#pragma unroll
    for (int c = 0; c < 8; c++) accl[s][op][c] = acc[c];
    if (op == 0) swl[s] = sw;
    __syncthreads();

    if (t < 128) {
        int c = t;
        float r = 0.f;
#pragma unroll
        for (int k = 0; k < 16; k++) r += accl[k][c >> 3][c & 7];
        float swt = 0.f;
#pragma unroll
        for (int k = 0; k < 16; k++) swt += swl[k];
        out[(size_t)n * HID + c] = r / swt;
    }
}

extern "C" void kernel_launch(void* const* d_in, const int* in_sizes, int n_in,
                              void* d_out, int out_size, void* d_ws, size_t ws_size,
                              hipStream_t stream) {
    const float* x       = (const float*)d_in[0];
    const float* adj     = (const float*)d_in[1];
    const float* W_heads = (const float*)d_in[2];
    const float* a_heads = (const float*)d_in[3];
    const float* W_out   = (const float*)d_in[4];
    const float* a_out   = (const float*)d_in[5];
    float* out = (float*)d_out;

    char* wsb = (char*)d_ws;
    size_t off = 0;
    auto alloc = [&](size_t bytes) {
        void* p = wsb + off;
        off += (bytes + 255) & ~(size_t)255;
        return p;
    };
    float* Wh   = (float*)alloc(sizeof(float) * (size_t)NH * N * HID);  // 24.576 MB
    u16*   Whb  = (u16*)  alloc(sizeof(u16)   * (size_t)NH * N * HID);
    float* hcat = (float*)alloc(sizeof(float) * (size_t)N * NH * HID);
    float* Wh2  = (float*)alloc(sizeof(float) * (size_t)N * HID);
    float* f1   = (float*)alloc(sizeof(float) * (size_t)NH * N);
    float* f2   = (float*)alloc(sizeof(float) * (size_t)NH * N);
    float* g1   = (float*)alloc(sizeof(float) * (size_t)N);
    float* g2   = (float*)alloc(sizeof(float) * (size_t)N);
    u16* nbr    = (u16*)  alloc(sizeof(u16)   * (size_t)N * NBR_CAP);
    int* ncnt   = (int*)  alloc(sizeof(int)   * (size_t)N);

    // partial[KSPLIT][N][HID] aliases Wh (same size; Wh's last reader calc_f
    // precedes gemm_out in stream order).
    float* partial = Wh;

    hipLaunchKernelGGL(build_nbr, dim3(N), dim3(256), 0, stream, adj, nbr, ncnt);
    hipLaunchKernelGGL(gemm_wh, dim3((N + 63) / 64, NH), dim3(256), 0, stream, x, W_heads, Wh, Whb);
    hipLaunchKernelGGL(calc_f, dim3(NH * N / 4), dim3(256), 0, stream, Wh, a_heads, f1, f2);
    hipLaunchKernelGGL(gat1, dim3(NH * N), dim3(256), 0, stream, Whb, f1, f2, nbr, ncnt, hcat);
    hipLaunchKernelGGL(gemm_out, dim3((N + 63) / 64, KSPLIT), dim3(256), 0, stream, hcat, W_out, partial);
    hipLaunchKernelGGL(reduce_wh2, dim3((N * HID / 4 + 255) / 256), dim3(256), 0, stream, partial, Wh2);
    hipLaunchKernelGGL(calc_g, dim3(N / 4), dim3(256), 0, stream, Wh2, a_out, g1, g2);
    hipLaunchKernelGGL(gat2, dim3(N), dim3(256), 0, stream, Wh2, g1, g2, nbr, ncnt, out);
}

// Round 7
// 345.109 us; speedup vs baseline: 1.1484x; 1.1484x over previous
//
#include <hip/hip_runtime.h>
#include <hip/hip_fp16.h>
#include <math.h>

#define N 6000
#define FIN 300
#define HID 128
#define NH 8
#define ALPHA 0.2f
#define NBR_CAP 512
#define KSPLIT 8

typedef unsigned short u16;
typedef unsigned int u32;

static __device__ __forceinline__ u16 f2bf(float f) {
    u32 u = __float_as_uint(f);
    u32 r = (u + 0x7fff + ((u >> 16) & 1)) >> 16;   // round-to-nearest-even
    return (u16)r;
}
static __device__ __forceinline__ u16 f2h(float f) {
    return __half_as_ushort(__float2half(f));
}

// K0: build neighbor lists; per-wave private segment, 1 barrier, float4 loads
__global__ void build_nbr(const float* __restrict__ adj,
                          u16* __restrict__ nbr,
                          int* __restrict__ ncnt) {
    int n = blockIdx.x;
    int t = threadIdx.x;
    int lane = t & 63, w = t >> 6;
    __shared__ u16 lbuf[4][256];
    __shared__ int wc[4];
    const int seg = N / 4;                 // 1500
    int start = w * seg, end = start + seg;
    const float* row = adj + (size_t)n * N;
    int cnt = 0;
    for (int base = start; base < end; base += 256) {
        int m0 = base + 4 * lane;
        float4 v = make_float4(0.f, 0.f, 0.f, 0.f);
        if (m0 < end) v = *(const float4*)(row + m0);
#pragma unroll
        for (int c = 0; c < 4; c++) {
            float vc = (c == 0) ? v.x : (c == 1) ? v.y : (c == 2) ? v.z : v.w;
            bool p = vc > 0.5f;
            unsigned long long mask = __ballot(p);
            if (p) {
                int pos = cnt + __popcll(mask & ((1ull << lane) - 1ull));
                if (pos < 256) lbuf[w][pos] = (u16)(m0 + c);
            }
            cnt += __popcll(mask);
        }
    }
    if (cnt > 256) cnt = 256;
    if (lane == 0) wc[w] = cnt;
    __syncthreads();
    int offset = 0;
    for (int i = 0; i < w; i++) offset += wc[i];
    for (int i = lane; i < cnt; i += 64) {
        int idx = offset + i;
        if (idx < NBR_CAP) nbr[(size_t)n * NBR_CAP + idx] = lbuf[w][i];
    }
    if (t == 0) {
        int total = wc[0] + wc[1] + wc[2] + wc[3];
        ncnt[n] = total < NBR_CAP ? total : NBR_CAP;
    }
}

// K1: Whb(bf16) = x @ W_heads, fused f1/f2 epilogue (fp32 accurate).
// fp32 Wh array eliminated: f computed in-register from fp32 acc.
__global__ void gemm_wh(const float* __restrict__ x,
                        const float* __restrict__ W,
                        const float* __restrict__ a_heads,
                        u16* __restrict__ Whb,
                        float* __restrict__ f1, float* __restrict__ f2) {
    int h = blockIdx.y;
    int n0 = blockIdx.x * 64;
    __shared__ float xs[64][21];
    __shared__ float bs[20][128];
    int t = threadIdx.x;
    int tx = t & 31, ty = t >> 5;
    float acc[8][4] = {};
    for (int k0 = 0; k0 < FIN; k0 += 20) {
        for (int i = t; i < 64 * 20; i += 256) {
            int r = i / 20, c = i - r * 20;
            int n = n0 + r;
            xs[r][c] = (n < N) ? x[(size_t)n * FIN + k0 + c] : 0.f;
        }
        for (int i = t; i < 20 * 128; i += 256) {
            int r = i >> 7, c = i & 127;
            bs[r][c] = W[((size_t)h * FIN + (k0 + r)) * HID + c];
        }
        __syncthreads();
#pragma unroll
        for (int kk = 0; kk < 20; kk++) {
            float b[4];
#pragma unroll
            for (int j = 0; j < 4; j++) b[j] = bs[kk][tx * 4 + j];
#pragma unroll
            for (int i = 0; i < 8; i++) {
                float a = xs[ty * 8 + i][kk];
#pragma unroll
                for (int j = 0; j < 4; j++) acc[i][j] += a * b[j];
            }
        }
        __syncthreads();
    }
    float a1c[4], a2c[4];
#pragma unroll
    for (int j = 0; j < 4; j++) {
        a1c[j] = a_heads[(size_t)h * 2 * HID + tx * 4 + j];
        a2c[j] = a_heads[(size_t)h * 2 * HID + HID + tx * 4 + j];
    }
    for (int i = 0; i < 8; i++) {
        int n = n0 + ty * 8 + i;
        float s1 = 0.f, s2 = 0.f;
#pragma unroll
        for (int j = 0; j < 4; j++) { s1 += acc[i][j] * a1c[j]; s2 += acc[i][j] * a2c[j]; }
        for (int d = 1; d <= 16; d <<= 1) { s1 += __shfl_xor(s1, d); s2 += __shfl_xor(s2, d); }
        if (n < N) {
            size_t ro = ((size_t)h * N + n) * HID + tx * 4;
            ushort4 b4;
            b4.x = f2bf(acc[i][0]); b4.y = f2bf(acc[i][1]);
            b4.z = f2bf(acc[i][2]); b4.w = f2bf(acc[i][3]);
            *(ushort4*)(Whb + ro) = b4;
            if (tx == 0) { f1[h * N + n] = s1; f2[h * N + n] = s2; }
        }
    }
}

// K3: layer-1 fused masked-softmax + PV (R4 form, the measured 188us config).
// 16 streams x 16 lanes x 8 cols; {w, byteoff} float2 in LDS; bf16 hi free.
__global__ void gat1(const u16* __restrict__ Whb,
                     const float* __restrict__ f1, const float* __restrict__ f2,
                     const u16* __restrict__ nbr,
                     const int* __restrict__ ncnt,
                     float* __restrict__ hcat) {
    int bid = blockIdx.x;
    int h = bid / N, n = bid - h * N;
    int t = threadIdx.x;
    int s = t >> 4, op = t & 15;
    int cnt = ncnt[n];
    const u16* lst = nbr + (size_t)n * NBR_CAP;
    __shared__ float2 wm[NBR_CAP];        // {weight, byte-offset bits}
    __shared__ float accl[16][16][9];     // padded
    __shared__ float swl[16];

    float f1c = f1[h * N + n];
    for (int i = t; i < cnt; i += 256) {
        int m = lst[i];
        float z = f1c + f2[h * N + m];
        z = (z >= 0.f) ? z : ALPHA * z;
        wm[i] = make_float2(__expf(z), __uint_as_float((u32)m << 8));
    }
    __syncthreads();

    const char* base = (const char*)(Whb + (size_t)h * N * HID) + (op << 4);
    float acc[8] = {};
    float sw = 0.f;
    int j = s;
    for (; j + 16 < cnt; j += 32) {
        float2 p0 = wm[j];
        float2 p1 = wm[j + 16];
        const uint4 va = *(const uint4*)(base + __float_as_uint(p0.y));
        const uint4 vb = *(const uint4*)(base + __float_as_uint(p1.y));
        float w0 = p0.x, w1 = p1.x;
        acc[0] += w0 * __uint_as_float(va.x << 16);
        acc[1] += w0 * __uint_as_float(va.x);
        acc[2] += w0 * __uint_as_float(va.y << 16);
        acc[3] += w0 * __uint_as_float(va.y);
        acc[4] += w0 * __uint_as_float(va.z << 16);
        acc[5] += w0 * __uint_as_float(va.z);
        acc[6] += w0 * __uint_as_float(va.w << 16);
        acc[7] += w0 * __uint_as_float(va.w);
        acc[0] += w1 * __uint_as_float(vb.x << 16);
        acc[1] += w1 * __uint_as_float(vb.x);
        acc[2] += w1 * __uint_as_float(vb.y << 16);
        acc[3] += w1 * __uint_as_float(vb.y);
        acc[4] += w1 * __uint_as_float(vb.z << 16);
        acc[5] += w1 * __uint_as_float(vb.z);
        acc[6] += w1 * __uint_as_float(vb.w << 16);
        acc[7] += w1 * __uint_as_float(vb.w);
        sw += w0 + w1;
    }
    if (j < cnt) {
        float2 p0 = wm[j];
        const uint4 va = *(const uint4*)(base + __float_as_uint(p0.y));
        float w0 = p0.x;
        acc[0] += w0 * __uint_as_float(va.x << 16);
        acc[1] += w0 * __uint_as_float(va.x);
        acc[2] += w0 * __uint_as_float(va.y << 16);
        acc[3] += w0 * __uint_as_float(va.y);
        acc[4] += w0 * __uint_as_float(va.z << 16);
        acc[5] += w0 * __uint_as_float(va.z);
        acc[6] += w0 * __uint_as_float(va.w << 16);
        acc[7] += w0 * __uint_as_float(va.w);
        sw += w0;
    }
#pragma unroll
    for (int c = 0; c < 8; c++) accl[s][op][c] = acc[c];
    if (op == 0) swl[s] = sw;
    __syncthreads();

    if (t < 128) {
        int c = t;
        float r = 0.f;
#pragma unroll
        for (int k = 0; k < 16; k++) r += accl[k][c >> 3][c & 7];
        float swt = 0.f;
#pragma unroll
        for (int k = 0; k < 16; k++) swt += swl[k];
        r /= swt;
        r = (r > 0.f) ? r : expm1f(r);
        hcat[(size_t)n * (NH * HID) + h * HID + c] = r;
    }
}

// K4: partial = hcat(6000x1024) @ W_out(1024x128), split-K over 8 slices.
__global__ void gemm_out(const float* __restrict__ hcat,
                         const float* __restrict__ W_out,
                         float* __restrict__ partial) {
    int n0 = blockIdx.x * 64;
    int ks = blockIdx.y;
    __shared__ float xs[64][17];
    __shared__ float bs[16][128];
    int t = threadIdx.x;
    int tx = t & 31, ty = t >> 5;
    float acc[8][4] = {};
    int kbeg = ks * 128, kend = kbeg + 128;
    for (int k0 = kbeg; k0 < kend; k0 += 16) {
        for (int i = t; i < 64 * 16; i += 256) {
            int r = i >> 4, c = i & 15;
            int n = n0 + r;
            xs[r][c] = (n < N) ? hcat[(size_t)n * 1024 + k0 + c] : 0.f;
        }
        for (int i = t; i < 16 * 128; i += 256) {
            int r = i >> 7, c = i & 127;
            bs[r][c] = W_out[(size_t)(k0 + r) * HID + c];
        }
        __syncthreads();
#pragma unroll
        for (int kk = 0; kk < 16; kk++) {
            float b[4];
#pragma unroll
            for (int j = 0; j < 4; j++) b[j] = bs[kk][tx * 4 + j];
#pragma unroll
            for (int i = 0; i < 8; i++) {
                float a = xs[ty * 8 + i][kk];
#pragma unroll
                for (int j = 0; j < 4; j++) acc[i][j] += a * b[j];
            }
        }
        __syncthreads();
    }
    float* pout = partial + (size_t)ks * N * HID;
    for (int i = 0; i < 8; i++) {
        int n = n0 + ty * 8 + i;
        if (n < N) {
#pragma unroll
            for (int j = 0; j < 4; j++)
                pout[(size_t)n * HID + tx * 4 + j] = acc[i][j];
        }
    }
}

// K4b: sum the 8 K-split partials -> fp16 Wh2h shadow; fused g1/g2.
// grid 750 x 256; block owns 8 full rows (1024 floats).
__global__ void reduce_wh2(const float* __restrict__ partial,
                           const float* __restrict__ a_out,
                           u16* __restrict__ Wh2h,
                           float* __restrict__ g1, float* __restrict__ g2) {
    int idx = blockIdx.x * 256 + threadIdx.x;      // float4 index
    float4 v = *(const float4*)(partial + 4 * (size_t)idx);
#pragma unroll
    for (int s = 1; s < KSPLIT; s++) {
        const float4 q = *(const float4*)(partial + (size_t)s * N * HID + 4 * (size_t)idx);
        v.x += q.x; v.y += q.y; v.z += q.z; v.w += q.w;
    }
    ushort4 h4;
    h4.x = f2h(v.x); h4.y = f2h(v.y); h4.z = f2h(v.z); h4.w = f2h(v.w);
    *(ushort4*)(Wh2h + 4 * (size_t)idx) = h4;

    int row = idx >> 5, cg = idx & 31;
    float p1 = v.x * a_out[4 * cg] + v.y * a_out[4 * cg + 1]
             + v.z * a_out[4 * cg + 2] + v.w * a_out[4 * cg + 3];
    float p2 = v.x * a_out[HID + 4 * cg] + v.y * a_out[HID + 4 * cg + 1]
             + v.z * a_out[HID + 4 * cg + 2] + v.w * a_out[HID + 4 * cg + 3];
    for (int d = 1; d <= 16; d <<= 1) { p1 += __shfl_xor(p1, d); p2 += __shfl_xor(p2, d); }
    if ((threadIdx.x & 31) == 0) { g1[row] = p1; g2[row] = p2; }
}

// K6: layer-2 fused masked-softmax + PV, fp16 gather (gat1 mirror).
__global__ void gat2(const u16* __restrict__ Wh2h,
                     const float* __restrict__ g1, const float* __restrict__ g2,
                     const u16* __restrict__ nbr,
                     const int* __restrict__ ncnt,
                     float* __restrict__ out) {
    int n = blockIdx.x, t = threadIdx.x;
    int s = t >> 4, op = t & 15;
    int cnt = ncnt[n];
    const u16* lst = nbr + (size_t)n * NBR_CAP;
    __shared__ float2 wm[NBR_CAP];
    __shared__ float accl[16][16][9];
    __shared__ float swl[16];

    float g1c = g1[n];
    for (int i = t; i < cnt; i += 256) {
        int m = lst[i];
        float z = g1c + g2[m];
        z = (z >= 0.f) ? z : ALPHA * z;
        wm[i] = make_float2(__expf(z), __uint_as_float((u32)m << 8));
    }
    __syncthreads();

    const char* base = (const char*)Wh2h + (op << 4);
    float acc[8] = {};
    float sw = 0.f;
    int j = s;
    for (; j + 16 < cnt; j += 32) {
        float2 p0 = wm[j];
        float2 p1 = wm[j + 16];
        const uint4 va = *(const uint4*)(base + __float_as_uint(p0.y));
        const uint4 vb = *(const uint4*)(base + __float_as_uint(p1.y));
        float w0 = p0.x, w1 = p1.x;
        acc[0] += w0 * __half2float(__ushort_as_half((u16)(va.x & 0xffff)));
        acc[1] += w0 * __half2float(__ushort_as_half((u16)(va.x >> 16)));
        acc[2] += w0 * __half2float(__ushort_as_half((u16)(va.y & 0xffff)));
        acc[3] += w0 * __half2float(__ushort_as_half((u16)(va.y >> 16)));
        acc[4] += w0 * __half2float(__ushort_as_half((u16)(va.z & 0xffff)));
        acc[5] += w0 * __half2float(__ushort_as_half((u16)(va.z >> 16)));
        acc[6] += w0 * __half2float(__ushort_as_half((u16)(va.w & 0xffff)));
        acc[7] += w0 * __half2float(__ushort_as_half((u16)(va.w >> 16)));
        acc[0] += w1 * __half2float(__ushort_as_half((u16)(vb.x & 0xffff)));
        acc[1] += w1 * __half2float(__ushort_as_half((u16)(vb.x >> 16)));
        acc[2] += w1 * __half2float(__ushort_as_half((u16)(vb.y & 0xffff)));
        acc[3] += w1 * __half2float(__ushort_as_half((u16)(vb.y >> 16)));
        acc[4] += w1 * __half2float(__ushort_as_half((u16)(vb.z & 0xffff)));
        acc[5] += w1 * __half2float(__ushort_as_half((u16)(vb.z >> 16)));
        acc[6] += w1 * __half2float(__ushort_as_half((u16)(vb.w & 0xffff)));
        acc[7] += w1 * __half2float(__ushort_as_half((u16)(vb.w >> 16)));
        sw += w0 + w1;
    }
    if (j < cnt) {
        float2 p0 = wm[j];
        const uint4 va = *(const uint4*)(base + __float_as_uint(p0.y));
        float w0 = p0.x;
        acc[0] += w0 * __half2float(__ushort_as_half((u16)(va.x & 0xffff)));
        acc[1] += w0 * __half2float(__ushort_as_half((u16)(va.x >> 16)));
        acc[2] += w0 * __half2float(__ushort_as_half((u16)(va.y & 0xffff)));
        acc[3] += w0 * __half2float(__ushort_as_half((u16)(va.y >> 16)));
        acc[4] += w0 * __half2float(__ushort_as_half((u16)(va.z & 0xffff)));
        acc[5] += w0 * __half2float(__ushort_as_half((u16)(va.z >> 16)));
        acc[6] += w0 * __half2float(__ushort_as_half((u16)(va.w & 0xffff)));
        acc[7] += w0 * __half2float(__ushort_as_half((u16)(va.w >> 16)));
        sw += w0;
    }
#pragma unroll
    for (int c = 0; c < 8; c++) accl[s][op][c] = acc[c];
    if (op == 0) swl[s] = sw;
    __syncthreads();

    if (t < 128) {
        int c = t;
        float r = 0.f;
#pragma unroll
        for (int k = 0; k < 16; k++) r += accl[k][c >> 3][c & 7];
        float swt = 0.f;
#pragma unroll
        for (int k = 0; k < 16; k++) swt += swl[k];
        out[(size_t)n * HID + c] = r / swt;
    }
}

extern "C" void kernel_launch(void* const* d_in, const int* in_sizes, int n_in,
                              void* d_out, int out_size, void* d_ws, size_t ws_size,
                              hipStream_t stream) {
    const float* x       = (const float*)d_in[0];
    const float* adj     = (const float*)d_in[1];
    const float* W_heads = (const float*)d_in[2];
    const float* a_heads = (const float*)d_in[3];
    const float* W_out   = (const float*)d_in[4];
    const float* a_out   = (const float*)d_in[5];
    float* out = (float*)d_out;

    char* wsb = (char*)d_ws;
    size_t off = 0;
    auto alloc = [&](size_t bytes) {
        void* p = wsb + off;
        off += (bytes + 255) & ~(size_t)255;
        return p;
    };
    float* partial = (float*)alloc(sizeof(float) * (size_t)KSPLIT * N * HID); // 24.576 MB
    u16*   Whb  = (u16*)  alloc(sizeof(u16)   * (size_t)NH * N * HID);
    float* hcat = (float*)alloc(sizeof(float) * (size_t)N * NH * HID);
    u16*   Wh2h = (u16*)  alloc(sizeof(u16)   * (size_t)N * HID);
    float* f1   = (float*)alloc(sizeof(float) * (size_t)NH * N);
    float* f2   = (float*)alloc(sizeof(float) * (size_t)NH * N);
    float* g1   = (float*)alloc(sizeof(float) * (size_t)N);
    float* g2   = (float*)alloc(sizeof(float) * (size_t)N);
    u16* nbr    = (u16*)  alloc(sizeof(u16)   * (size_t)N * NBR_CAP);
    int* ncnt   = (int*)  alloc(sizeof(int)   * (size_t)N);

    hipLaunchKernelGGL(build_nbr, dim3(N), dim3(256), 0, stream, adj, nbr, ncnt);
    hipLaunchKernelGGL(gemm_wh, dim3((N + 63) / 64, NH), dim3(256), 0, stream,
                       x, W_heads, a_heads, Whb, f1, f2);
    hipLaunchKernelGGL(gat1, dim3(NH * N), dim3(256), 0, stream, Whb, f1, f2, nbr, ncnt, hcat);
    hipLaunchKernelGGL(gemm_out, dim3((N + 63) / 64, KSPLIT), dim3(256), 0, stream,
                       hcat, W_out, partial);
    hipLaunchKernelGGL(reduce_wh2, dim3(N * HID / 4 / 256), dim3(256), 0, stream,
                       partial, a_out, Wh2h, g1, g2);
    hipLaunchKernelGGL(gat2, dim3(N), dim3(256), 0, stream, Wh2h, g1, g2, nbr, ncnt, out);
}